// Round 3
// baseline (1172.768 us; speedup 1.0000x reference)
//
#include <hip/hip_runtime.h>
#include <math.h>

// B=4, C=64, OUT=64, H=256, W=256, M1=32, M2=32, HID=64, COORD=65

__device__ __forceinline__ float gelu_f(float v) {
    return 0.5f * v * (1.0f + erff(v * 0.70710678118654752440f));
}

// ---------------------------------------------------------------------------
// GEMM tile: 256 threads compute [64 px] x [64 outs], K=64 (+optional row 64).
// act: LDS [64][68]. W: [.][wstride] (LDS=68 or global=64), rows k, cols o.
// bias: [64] or nullptr. Thread (po=t>>4, oo=t&15) -> acc[4 px][4 outs].
// ---------------------------------------------------------------------------
__device__ __forceinline__ void gemm_tile(
    const float* __restrict__ act,
    const float* __restrict__ W, const int wstride,
    const float* __restrict__ bias,
    bool extra, int t, float acc[4][4])
{
    const int po = t >> 4, oo = t & 15;
    if (bias) {
        const float4 bv = *(const float4*)&bias[oo * 4];
#pragma unroll
        for (int i = 0; i < 4; ++i) {
            acc[i][0] = bv.x; acc[i][1] = bv.y; acc[i][2] = bv.z; acc[i][3] = bv.w;
        }
    } else {
#pragma unroll
        for (int i = 0; i < 4; ++i)
            acc[i][0] = acc[i][1] = acc[i][2] = acc[i][3] = 0.f;
    }
#pragma unroll
    for (int k4 = 0; k4 < 16; ++k4) {
        float4 a[4], w[4];
#pragma unroll
        for (int i = 0; i < 4; ++i)
            a[i] = *(const float4*)&act[(po * 4 + i) * 68 + k4 * 4];
#pragma unroll
        for (int q = 0; q < 4; ++q)
            w[q] = *(const float4*)&W[(k4 * 4 + q) * wstride + oo * 4];
#pragma unroll
        for (int i = 0; i < 4; ++i) {
            const float aq[4] = {a[i].x, a[i].y, a[i].z, a[i].w};
#pragma unroll
            for (int q = 0; q < 4; ++q) {
                acc[i][0] = fmaf(aq[q], w[q].x, acc[i][0]);
                acc[i][1] = fmaf(aq[q], w[q].y, acc[i][1]);
                acc[i][2] = fmaf(aq[q], w[q].z, acc[i][2]);
                acc[i][3] = fmaf(aq[q], w[q].w, acc[i][3]);
            }
        }
    }
    if (extra) {
        const float4 wv = *(const float4*)&W[64 * wstride + oo * 4];
#pragma unroll
        for (int i = 0; i < 4; ++i) {
            const float av = act[(po * 4 + i) * 68 + 64];
            acc[i][0] = fmaf(av, wv.x, acc[i][0]);
            acc[i][1] = fmaf(av, wv.y, acc[i][1]);
            acc[i][2] = fmaf(av, wv.z, acc[i][2]);
            acc[i][3] = fmaf(av, wv.w, acc[i][3]);
        }
    }
}

__device__ __forceinline__ float4 gelu4(const float a[4]) {
    float4 r;
    r.x = gelu_f(a[0]); r.y = gelu_f(a[1]); r.z = gelu_f(a[2]); r.w = gelu_f(a[3]);
    return r;
}

// Stage a [rows x 64] global weight matrix into LDS [rows x 68].
__device__ __forceinline__ void stage_w(const float* __restrict__ W, float* __restrict__ sW,
                                        int rows, int t) {
    const int nf4 = rows * 16;
    for (int idx = t; idx < nf4; idx += 256) {
        const int kk = idx >> 4, f = idx & 15;
        *(float4*)&sW[kk * 68 + f * 4] = *(const float4*)&W[kk * 64 + f * 4];
    }
}

// K0: transpose mixer/skip weights (once). mwT[c][o] = mw[o][c].
__global__ void k_tr(const float* __restrict__ mw, const float* __restrict__ scw,
                     float* __restrict__ mwT, float* __restrict__ scwT) {
    const int t = threadIdx.x;
#pragma unroll
    for (int r = 0; r < 16; ++r) {
        const int idx = r * 256 + t;
        const int o = idx >> 6, c = idx & 63;
        mwT[c * 64 + o] = mw[o * 64 + c];
        scwT[c * 64 + o] = scw[o * 64 + c];
    }
}

// K1: wb basis. grid = B*H*4 (4096): (b,h,wq). 64 px/block.
__global__ __launch_bounds__(256) void k_wb_mlp(
    const float* __restrict__ x,
    const float* __restrict__ W0, const float* __restrict__ b0,
    const float* __restrict__ W1, const float* __restrict__ b1,
    const float* __restrict__ W2, const float* __restrict__ b2,
    float* __restrict__ wb_re, float* __restrict__ wb_im)
{
    __shared__ __align__(16) float a0[64 * 68];
    __shared__ __align__(16) float a1[64 * 68];
    __shared__ __align__(16) float sW[65 * 68];
    const int blk = blockIdx.x;
    const int b = blk >> 10, h = (blk >> 2) & 255, wq = blk & 3;
    const int w0 = wq * 64;
    const int t = threadIdx.x;
#pragma unroll
    for (int r = 0; r < 4; ++r) {
        const int idx = r * 256 + t;
        const int c = idx >> 4, wg = idx & 15;
        const float4 v = *(const float4*)&x[((size_t)(b * 64 + c) * 256 + h) * 256 + w0 + wg * 4];
        a0[(wg * 4 + 0) * 68 + c] = v.x;
        a0[(wg * 4 + 1) * 68 + c] = v.y;
        a0[(wg * 4 + 2) * 68 + c] = v.z;
        a0[(wg * 4 + 3) * 68 + c] = v.w;
    }
    if (t < 64) a0[t * 68 + 64] = (float)(w0 + t) * (2.0f / 255.0f) - 1.0f;
    stage_w(W0, sW, 65, t);
    __syncthreads();

    const int po = t >> 4, oo = t & 15;
    float acc[4][4];
    gemm_tile(a0, sW, 68, b0, true, t, acc);
    __syncthreads();
#pragma unroll
    for (int i = 0; i < 4; ++i)
        *(float4*)&a1[(po * 4 + i) * 68 + oo * 4] = gelu4(acc[i]);
    stage_w(W1, sW, 64, t);
    __syncthreads();
    gemm_tile(a1, sW, 68, b1, false, t, acc);
    __syncthreads();
#pragma unroll
    for (int i = 0; i < 4; ++i)
        *(float4*)&a0[(po * 4 + i) * 68 + oo * 4] = gelu4(acc[i]);
    stage_w(W2, sW, 64, t);
    __syncthreads();
    gemm_tile(a0, sW, 68, b2, false, t, acc);

    const size_t pixbase = (size_t)(b * 256 + h) * 256 + w0;
#pragma unroll
    for (int i = 0; i < 4; ++i) {
        const size_t pix = pixbase + po * 4 + i;
        float4 v; v.x = acc[i][0]; v.y = acc[i][1]; v.z = acc[i][2]; v.w = acc[i][3];
        if (oo < 8) *(float4*)&wb_re[pix * 32 + oo * 4] = v;
        else        *(float4*)&wb_im[pix * 32 + (oo - 8) * 4] = v;
    }
}

// K2: tfw along W. grid = B*H (1024). Writes tfwM[b][m][h][c][{re,im}].
__global__ __launch_bounds__(256) void k_tfw(
    const float* __restrict__ x,
    const float* __restrict__ wb_re, const float* __restrict__ wb_im,
    float* __restrict__ tfwM)
{
    __shared__ float wr[256 * 32];
    __shared__ float wi[256 * 32];
    const int bh = blockIdx.x;
    const int b = bh >> 8, h = bh & 255;
    const int t = threadIdx.x;
    const size_t wboff = (size_t)bh * 8192;
#pragma unroll
    for (int i = 0; i < 8; ++i) {
        const int idx = i * 256 + t;
        *(float4*)&wr[idx * 4] = *(const float4*)&wb_re[wboff + (size_t)idx * 4];
        *(float4*)&wi[idx * 4] = *(const float4*)&wb_im[wboff + (size_t)idx * 4];
    }
    __syncthreads();
    const int m = t & 31, cg = t >> 5;
    float ar[8], ai[8];
#pragma unroll
    for (int i = 0; i < 8; ++i) { ar[i] = 0.f; ai[i] = 0.f; }
    for (int w4 = 0; w4 < 256; w4 += 4) {
        float4 xv[8];
#pragma unroll
        for (int i = 0; i < 8; ++i)
            xv[i] = *(const float4*)&x[((size_t)(b * 64 + cg * 8 + i) * 256 + h) * 256 + w4];
#pragma unroll
        for (int q = 0; q < 4; ++q) {
            const float wrv = wr[(w4 + q) * 32 + m];
            const float wiv = wi[(w4 + q) * 32 + m];
#pragma unroll
            for (int i = 0; i < 8; ++i) {
                const float xq = (q == 0) ? xv[i].x : (q == 1) ? xv[i].y : (q == 2) ? xv[i].z : xv[i].w;
                ar[i] = fmaf(xq, wrv, ar[i]);
                ai[i] = fmaf(xq, wiv, ai[i]);
            }
        }
    }
    // write 64B contiguous per lane: (b,m,h, c=cg*8.., interleaved re/im)
    const size_t base = (((size_t)(b * 32 + m) * 256 + h) * 64 + cg * 8) * 2;
#pragma unroll
    for (int p = 0; p < 4; ++p) {
        float4 v;
        v.x = ar[p * 2]; v.y = ai[p * 2]; v.z = ar[p * 2 + 1]; v.w = ai[p * 2 + 1];
        *(float4*)&tfwM[base + p * 4] = v;
    }
}

// K3: hb basis. grid = B*M2*4 (512): (bm,hq). Reads tfwM real parts.
__global__ __launch_bounds__(256) void k_hb_mlp(
    const float* __restrict__ tfwM,
    const float* __restrict__ W0, const float* __restrict__ b0,
    const float* __restrict__ W1, const float* __restrict__ b1,
    const float* __restrict__ W2, const float* __restrict__ b2,
    float* __restrict__ hb_re, float* __restrict__ hb_im)
{
    __shared__ __align__(16) float a0[64 * 68];
    __shared__ __align__(16) float a1[64 * 68];
    __shared__ __align__(16) float sW[65 * 68];
    const int blk = blockIdx.x;
    const int bm = blk >> 2, hq = blk & 3;
    const int h0 = hq * 64;
    const int t = threadIdx.x;
#pragma unroll
    for (int r = 0; r < 4; ++r) {
        const int idx = r * 256 + t;
        const int p = idx >> 4, f = idx & 15;
        const float* src = &tfwM[(size_t)(bm * 256 + h0 + p) * 128 + f * 8];
        const float4 u0 = *(const float4*)&src[0];
        const float4 u1 = *(const float4*)&src[4];
        a0[p * 68 + f * 4 + 0] = u0.x;
        a0[p * 68 + f * 4 + 1] = u0.z;
        a0[p * 68 + f * 4 + 2] = u1.x;
        a0[p * 68 + f * 4 + 3] = u1.z;
    }
    if (t < 64) a0[t * 68 + 64] = (float)(h0 + t) * (2.0f / 255.0f) - 1.0f;
    stage_w(W0, sW, 65, t);
    __syncthreads();

    const int po = t >> 4, oo = t & 15;
    float acc[4][4];
    gemm_tile(a0, sW, 68, b0, true, t, acc);
    __syncthreads();
#pragma unroll
    for (int i = 0; i < 4; ++i)
        *(float4*)&a1[(po * 4 + i) * 68 + oo * 4] = gelu4(acc[i]);
    stage_w(W1, sW, 64, t);
    __syncthreads();
    gemm_tile(a1, sW, 68, b1, false, t, acc);
    __syncthreads();
#pragma unroll
    for (int i = 0; i < 4; ++i)
        *(float4*)&a0[(po * 4 + i) * 68 + oo * 4] = gelu4(acc[i]);
    stage_w(W2, sW, 64, t);
    __syncthreads();
    gemm_tile(a0, sW, 68, b2, false, t, acc);

    const size_t pixbase = (size_t)bm * 256 + h0;
#pragma unroll
    for (int i = 0; i < 4; ++i) {
        const size_t pix = pixbase + po * 4 + i;
        float4 v; v.x = acc[i][0]; v.y = acc[i][1]; v.z = acc[i][2]; v.w = acc[i][3];
        if (oo < 8) *(float4*)&hb_re[pix * 32 + oo * 4] = v;
        else        *(float4*)&hb_im[pix * 32 + (oo - 8) * 4] = v;
    }
}

// K4: tfhw[b,c,k,m] = sum_h tfwM[b,m,h,c] * hb[b,m,h,k]. grid = 256: (bm,chalf).
__global__ __launch_bounds__(256) void k_tfhw2(
    const float* __restrict__ tfwM,
    const float* __restrict__ hb_re, const float* __restrict__ hb_im,
    float* __restrict__ tfhw_re, float* __restrict__ tfhw_im)
{
    __shared__ float hr[256 * 32];
    __shared__ float hi2[256 * 32];
    __shared__ float slab[32 * 64];
    const int blk = blockIdx.x;
    const int bm = blk >> 1, chalf = blk & 1;
    const int b = bm >> 5, m = bm & 31;
    const int t = threadIdx.x;
    const size_t hboff = (size_t)bm * 8192;
#pragma unroll
    for (int i = 0; i < 8; ++i) {
        const int idx = i * 256 + t;
        *(float4*)&hr[idx * 4] = *(const float4*)&hb_re[hboff + (size_t)idx * 4];
        *(float4*)&hi2[idx * 4] = *(const float4*)&hb_im[hboff + (size_t)idx * 4];
    }
    const int k = t & 31, cq = t >> 5;   // c = chalf*32 + cq*4 + i
    float accr[4] = {0.f, 0.f, 0.f, 0.f}, acci[4] = {0.f, 0.f, 0.f, 0.f};
    const size_t tbase = (size_t)bm * 256 * 128;
    for (int ht = 0; ht < 8; ++ht) {
        __syncthreads();
#pragma unroll
        for (int r = 0; r < 2; ++r) {
            const int q = r * 256 + t;           // 0..511
            const int hl = q >> 3, f = q & 7;
            *(float4*)&slab[hl * 64 + f * 4] =
                *(const float4*)&tfwM[tbase + (size_t)(ht * 32 + hl) * 128 + chalf * 64 + f * 4];
        }
        __syncthreads();
#pragma unroll 8
        for (int hl = 0; hl < 32; ++hl) {
            const int h = ht * 32 + hl;
            const float hrv = hr[h * 32 + k];
            const float hiv = hi2[h * 32 + k];
            const float4 u0 = *(const float4*)&slab[hl * 64 + cq * 8];
            const float4 u1 = *(const float4*)&slab[hl * 64 + cq * 8 + 4];
            accr[0] = fmaf(u0.x, hrv, fmaf(-u0.y, hiv, accr[0]));
            acci[0] = fmaf(u0.x, hiv, fmaf( u0.y, hrv, acci[0]));
            accr[1] = fmaf(u0.z, hrv, fmaf(-u0.w, hiv, accr[1]));
            acci[1] = fmaf(u0.z, hiv, fmaf( u0.w, hrv, acci[1]));
            accr[2] = fmaf(u1.x, hrv, fmaf(-u1.y, hiv, accr[2]));
            acci[2] = fmaf(u1.x, hiv, fmaf( u1.y, hrv, acci[2]));
            accr[3] = fmaf(u1.z, hrv, fmaf(-u1.w, hiv, accr[3]));
            acci[3] = fmaf(u1.z, hiv, fmaf( u1.w, hrv, acci[3]));
        }
    }
#pragma unroll
    for (int i = 0; i < 4; ++i) {
        const int c = chalf * 32 + cq * 4 + i;
        const size_t po = ((size_t)(b * 64 + c) * 32 + k) * 32 + m;
        tfhw_re[po] = accr[i];
        tfhw_im[po] = acci[i];
    }
}

// K5: proc[b,o,k,m] = sum_c tfhw[b,c,k,m] * Wf[c,o,k,m]. grid = 256.
__global__ __launch_bounds__(256) void k_proc(
    const float* __restrict__ tfhw_re, const float* __restrict__ tfhw_im,
    const float* __restrict__ Wf_re, const float* __restrict__ Wf_im,
    float* __restrict__ proc_re, float* __restrict__ proc_im)
{
    const int o = blockIdx.x >> 2, kq = blockIdx.x & 3;
    const int t = threadIdx.x;
    const int mo = kq * 256 + t;
    float accr[4] = {0.f, 0.f, 0.f, 0.f}, acci[4] = {0.f, 0.f, 0.f, 0.f};
    for (int c = 0; c < 64; ++c) {
        const float wfr = Wf_re[(size_t)(c * 64 + o) * 1024 + mo];
        const float wfi = Wf_im[(size_t)(c * 64 + o) * 1024 + mo];
#pragma unroll
        for (int bb = 0; bb < 4; ++bb) {
            const float tr = tfhw_re[(size_t)(bb * 64 + c) * 1024 + mo];
            const float ti = tfhw_im[(size_t)(bb * 64 + c) * 1024 + mo];
            accr[bb] = fmaf(tr, wfr, fmaf(-ti, wfi, accr[bb]));
            acci[bb] = fmaf(tr, wfi, fmaf(ti, wfr, acci[bb]));
        }
    }
#pragma unroll
    for (int bb = 0; bb < 4; ++bb) {
        proc_re[(size_t)(bb * 64 + o) * 1024 + mo] = accr[bb];
        proc_im[(size_t)(bb * 64 + o) * 1024 + mo] = acci[bb];
    }
}

// K6: recT[b,h,k64,o64]: k<32 -> Re(sum_k' proc*conj(hb)) at m=k, k>=32 -> Im.
// grid = 512: (b,m,hq). block: (o=t&63, hg=t>>6), 16 h each.
__global__ __launch_bounds__(256) void k_rec2(
    const float* __restrict__ proc_re, const float* __restrict__ proc_im,
    const float* __restrict__ hb_re, const float* __restrict__ hb_im,
    float* __restrict__ recT)
{
    __shared__ float lhr[64 * 32];
    __shared__ float lhi[64 * 32];
    const int blk = blockIdx.x;
    const int bm = blk >> 2, hq = blk & 3;
    const int b = bm >> 5, m = bm & 31;
    const int t = threadIdx.x;
#pragma unroll
    for (int r = 0; r < 2; ++r) {
        const int q = r * 256 + t;       // 0..511
        const int hl = q >> 3, f = q & 7;
        const size_t src = (size_t)bm * 8192 + (size_t)(hq * 64 + hl) * 32 + f * 4;
        *(float4*)&lhr[hl * 32 + f * 4] = *(const float4*)&hb_re[src];
        *(float4*)&lhi[hl * 32 + f * 4] = *(const float4*)&hb_im[src];
    }
    const int o = t & 63, hg = t >> 6;
    float Pr[32], Pi[32];
#pragma unroll
    for (int k = 0; k < 32; ++k) {
        const size_t pa = ((size_t)(b * 64 + o) * 32 + k) * 32 + m;
        Pr[k] = proc_re[pa];
        Pi[k] = proc_im[pa];
    }
    __syncthreads();
    for (int hh = 0; hh < 16; ++hh) {
        const int hl = hg * 16 + hh;
        float ar = 0.f, ai = 0.f;
#pragma unroll
        for (int k = 0; k < 32; ++k) {
            const float hrv = lhr[hl * 32 + k], hiv = lhi[hl * 32 + k];
            ar = fmaf(Pr[k], hrv, fmaf(Pi[k], hiv, ar));
            ai = fmaf(Pi[k], hrv, fmaf(-Pr[k], hiv, ai));
        }
        const int h = hq * 64 + hl;
        const size_t rb = (size_t)(b * 256 + h) * 64;
        recT[(rb + m) * 64 + o]      = ar;
        recT[(rb + 32 + m) * 64 + o] = ai;
    }
}

// K7: spatial + mixer + skip + gelus as three LDS GEMM tiles.
// grid = B*H*4 (4096): (b,h,wq). 64 px/block.
__global__ __launch_bounds__(256) void k_final3(
    const float* __restrict__ x,
    const float* __restrict__ wb_re, const float* __restrict__ wb_im,
    const float* __restrict__ recT,
    const float* __restrict__ mwT, const float* __restrict__ mb,
    const float* __restrict__ scwT, const float* __restrict__ scb,
    float* __restrict__ out)
{
    __shared__ __align__(16) float sA[64 * 68];  // wb, then mwT
    __shared__ __align__(16) float sB[64 * 68];  // recT, then scwT
    __shared__ __align__(16) float sX[64 * 68];  // x (px rows, c cols)
    __shared__ __align__(16) float sS[64 * 68];  // spatial
    const int blk = blockIdx.x;
    const int b = blk >> 10, h = (blk >> 2) & 255, wq = blk & 3;
    const int w0 = wq * 64;
    const int t = threadIdx.x;
    const size_t pixbase = (size_t)(b * 256 + h) * 256 + w0;

    // stage wb: sA[p][0..31]=wr, [32..63]=wi
#pragma unroll
    for (int r = 0; r < 2; ++r) {
        const int idx = r * 256 + t;
        const int p = idx >> 3, mq = idx & 7;
        *(float4*)&sA[p * 68 + mq * 4]      = *(const float4*)&wb_re[(pixbase + p) * 32 + mq * 4];
        *(float4*)&sA[p * 68 + 32 + mq * 4] = *(const float4*)&wb_im[(pixbase + p) * 32 + mq * 4];
    }
    // stage recT tile: sB[k][o]
    const size_t recbase = (size_t)(b * 256 + h) * 64 * 64;
#pragma unroll
    for (int r = 0; r < 4; ++r) {
        const int idx = r * 256 + t;
        const int kk = idx >> 4, oq = idx & 15;
        *(float4*)&sB[kk * 68 + oq * 4] = *(const float4*)&recT[recbase + (size_t)kk * 64 + oq * 4];
    }
    // stage x transposed: sX[p][c]
#pragma unroll
    for (int r = 0; r < 4; ++r) {
        const int idx = r * 256 + t;
        const int c = idx >> 4, wg = idx & 15;
        const float4 v = *(const float4*)&x[((size_t)(b * 64 + c) * 256 + h) * 256 + w0 + wg * 4];
        sX[(wg * 4 + 0) * 68 + c] = v.x;
        sX[(wg * 4 + 1) * 68 + c] = v.y;
        sX[(wg * 4 + 2) * 68 + c] = v.z;
        sX[(wg * 4 + 3) * 68 + c] = v.w;
    }
    __syncthreads();

    const int po = t >> 4, oo = t & 15;
    float acc[4][4];
    // phase A: spatial = (wb . recT) / 65536
    gemm_tile(sA, sB, 68, nullptr, false, t, acc);
    __syncthreads();   // everyone done reading sA/sB
#pragma unroll
    for (int i = 0; i < 4; ++i) {
        float4 v;
        v.x = acc[i][0] * (1.0f / 65536.0f);
        v.y = acc[i][1] * (1.0f / 65536.0f);
        v.z = acc[i][2] * (1.0f / 65536.0f);
        v.w = acc[i][3] * (1.0f / 65536.0f);
        *(float4*)&sS[(po * 4 + i) * 68 + oo * 4] = v;
    }
    stage_w(mwT, sA, 64, t);
    stage_w(scwT, sB, 64, t);
    __syncthreads();

    // phase B: mixer + gelu
    float y[4][4];
    gemm_tile(sS, sA, 68, mb, false, t, y);
#pragma unroll
    for (int i = 0; i < 4; ++i)
#pragma unroll
        for (int j = 0; j < 4; ++j) y[i][j] = gelu_f(y[i][j]);
    // phase C: skip
    gemm_tile(sX, sB, 68, scb, false, t, acc);

#pragma unroll
    for (int j = 0; j < 4; ++j) {
        float4 v;
        v.x = gelu_f(y[0][j] + acc[0][j]);
        v.y = gelu_f(y[1][j] + acc[1][j]);
        v.z = gelu_f(y[2][j] + acc[2][j]);
        v.w = gelu_f(y[3][j] + acc[3][j]);
        *(float4*)&out[((size_t)(b * 64 + oo * 4 + j) * 256 + h) * 256 + w0 + po * 4] = v;
    }
}

extern "C" void kernel_launch(void* const* d_in, const int* in_sizes, int n_in,
                              void* d_out, int out_size, void* d_ws, size_t ws_size,
                              hipStream_t stream) {
    const float* x    = (const float*)d_in[0];
    const float* wW0  = (const float*)d_in[1];
    const float* wb0  = (const float*)d_in[2];
    const float* wW1  = (const float*)d_in[3];
    const float* wb1  = (const float*)d_in[4];
    const float* wW2  = (const float*)d_in[5];
    const float* wb2  = (const float*)d_in[6];
    const float* hW0  = (const float*)d_in[7];
    const float* hb0  = (const float*)d_in[8];
    const float* hW1  = (const float*)d_in[9];
    const float* hb1  = (const float*)d_in[10];
    const float* hW2  = (const float*)d_in[11];
    const float* hb2  = (const float*)d_in[12];
    const float* Wf_re = (const float*)d_in[13];
    const float* Wf_im = (const float*)d_in[14];
    const float* mw   = (const float*)d_in[15];
    const float* mbv  = (const float*)d_in[16];
    const float* scw  = (const float*)d_in[17];
    const float* scb  = (const float*)d_in[18];

    float* ws = (float*)d_ws;
    float* wb_re   = ws;                        // 8388608
    float* wb_im   = wb_re + 8388608;           // 8388608
    float* tfwM    = wb_im + 8388608;           // 4194304  (B,M2,H,C,{re,im})
    float* hb_re   = tfwM + 4194304;            // 1048576
    float* hb_im   = hb_re + 1048576;           // 1048576
    float* tfhw_re = hb_im + 1048576;           // 262144
    float* tfhw_im = tfhw_re + 262144;          // 262144
    float* proc_re = tfhw_im + 262144;          // 262144
    float* proc_im = proc_re + 262144;          // 262144
    float* recT    = proc_im + 262144;          // 4194304  (B,H,64,64)
    float* mwT     = recT + 4194304;            // 4096
    float* scwT    = mwT + 4096;                // 4096
    // total ~28.3M floats = 113.3 MB

    k_tr<<<1, 256, 0, stream>>>(mw, scw, mwT, scwT);
    k_wb_mlp<<<4096, 256, 0, stream>>>(x, wW0, wb0, wW1, wb1, wW2, wb2, wb_re, wb_im);
    k_tfw<<<1024, 256, 0, stream>>>(x, wb_re, wb_im, tfwM);
    k_hb_mlp<<<512, 256, 0, stream>>>(tfwM, hW0, hb0, hW1, hb1, hW2, hb2, hb_re, hb_im);
    k_tfhw2<<<256, 256, 0, stream>>>(tfwM, hb_re, hb_im, tfhw_re, tfhw_im);
    k_proc<<<256, 256, 0, stream>>>(tfhw_re, tfhw_im, Wf_re, Wf_im, proc_re, proc_im);
    k_rec2<<<512, 256, 0, stream>>>(proc_re, proc_im, hb_re, hb_im, recT);
    k_final3<<<4096, 256, 0, stream>>>(x, wb_re, wb_im, recT, mwT, mbv, scwT, scb,
                                       (float*)d_out);
}

// Round 4
// 375.358 us; speedup vs baseline: 3.1244x; 3.1244x over previous
//
#include <hip/hip_runtime.h>
#include <math.h>

// B=4, C=64, OUT=64, H=256, W=256, M1=32, M2=32, HID=64, COORD=65

typedef __attribute__((ext_vector_type(8))) short bf16x8;
typedef __attribute__((ext_vector_type(4))) float f32x4;

__device__ __forceinline__ float gelu_f(float v) {
    return 0.5f * v * (1.0f + erff(v * 0.70710678118654752440f));
}

__device__ __forceinline__ unsigned short f2b(float f) {
    union { float f; unsigned int u; } v; v.f = f;
    unsigned int u = v.u + 0x7FFFu + ((v.u >> 16) & 1u);   // RNE
    return (unsigned short)(u >> 16);
}
__device__ __forceinline__ float b2f(unsigned short b) {
    union { unsigned int u; float f; } v; v.u = ((unsigned int)b) << 16;
    return v.f;
}

// ---------------------------------------------------------------------------
// fp32 GEMM tile (for the two MLP kernels): 256 threads, [64 px] x [64 outs].
// act: LDS [64][68]. W: LDS [rows][68]. Thread (po=t>>4, oo=t&15).
// ---------------------------------------------------------------------------
__device__ __forceinline__ void gemm_tile(
    const float* __restrict__ act,
    const float* __restrict__ W,
    const float* __restrict__ bias,
    bool extra, int t, float acc[4][4])
{
    const int po = t >> 4, oo = t & 15;
    const float4 bv = *(const float4*)&bias[oo * 4];
#pragma unroll
    for (int i = 0; i < 4; ++i) {
        acc[i][0] = bv.x; acc[i][1] = bv.y; acc[i][2] = bv.z; acc[i][3] = bv.w;
    }
#pragma unroll
    for (int k4 = 0; k4 < 16; ++k4) {
        float4 a[4], w[4];
#pragma unroll
        for (int i = 0; i < 4; ++i)
            a[i] = *(const float4*)&act[(po * 4 + i) * 68 + k4 * 4];
#pragma unroll
        for (int q = 0; q < 4; ++q)
            w[q] = *(const float4*)&W[(k4 * 4 + q) * 68 + oo * 4];
#pragma unroll
        for (int i = 0; i < 4; ++i) {
            const float aq[4] = {a[i].x, a[i].y, a[i].z, a[i].w};
#pragma unroll
            for (int q = 0; q < 4; ++q) {
                acc[i][0] = fmaf(aq[q], w[q].x, acc[i][0]);
                acc[i][1] = fmaf(aq[q], w[q].y, acc[i][1]);
                acc[i][2] = fmaf(aq[q], w[q].z, acc[i][2]);
                acc[i][3] = fmaf(aq[q], w[q].w, acc[i][3]);
            }
        }
    }
    if (extra) {
        const float4 wv = *(const float4*)&W[64 * 68 + oo * 4];
#pragma unroll
        for (int i = 0; i < 4; ++i) {
            const float av = act[(po * 4 + i) * 68 + 64];
            acc[i][0] = fmaf(av, wv.x, acc[i][0]);
            acc[i][1] = fmaf(av, wv.y, acc[i][1]);
            acc[i][2] = fmaf(av, wv.z, acc[i][2]);
            acc[i][3] = fmaf(av, wv.w, acc[i][3]);
        }
    }
}

__device__ __forceinline__ float4 gelu4(const float a[4]) {
    float4 r;
    r.x = gelu_f(a[0]); r.y = gelu_f(a[1]); r.z = gelu_f(a[2]); r.w = gelu_f(a[3]);
    return r;
}

__device__ __forceinline__ void stage_w(const float* __restrict__ W, float* __restrict__ sW,
                                        int rows, int t) {
    const int nf4 = rows * 16;
    for (int idx = t; idx < nf4; idx += 256) {
        const int kk = idx >> 4, f = idx & 15;
        *(float4*)&sW[kk * 68 + f * 4] = *(const float4*)&W[kk * 64 + f * 4];
    }
}

// K1: wb basis. grid = B*H*4 (4096). Output wb_bf[pix][64] bf16 (32 re | 32 im).
__global__ __launch_bounds__(256) void k_wb_mlp(
    const float* __restrict__ x,
    const float* __restrict__ W0, const float* __restrict__ b0,
    const float* __restrict__ W1, const float* __restrict__ b1,
    const float* __restrict__ W2, const float* __restrict__ b2,
    unsigned short* __restrict__ wb_bf)
{
    __shared__ __align__(16) float a0[64 * 68];
    __shared__ __align__(16) float a1[64 * 68];
    __shared__ __align__(16) float sW[65 * 68];
    const int blk = blockIdx.x;
    const int b = blk >> 10, h = (blk >> 2) & 255, wq = blk & 3;
    const int w0 = wq * 64;
    const int t = threadIdx.x;
#pragma unroll
    for (int r = 0; r < 4; ++r) {
        const int idx = r * 256 + t;
        const int c = idx >> 4, wg = idx & 15;
        const float4 v = *(const float4*)&x[((size_t)(b * 64 + c) * 256 + h) * 256 + w0 + wg * 4];
        a0[(wg * 4 + 0) * 68 + c] = v.x;
        a0[(wg * 4 + 1) * 68 + c] = v.y;
        a0[(wg * 4 + 2) * 68 + c] = v.z;
        a0[(wg * 4 + 3) * 68 + c] = v.w;
    }
    if (t < 64) a0[t * 68 + 64] = (float)(w0 + t) * (2.0f / 255.0f) - 1.0f;
    stage_w(W0, sW, 65, t);
    __syncthreads();

    const int po = t >> 4, oo = t & 15;
    float acc[4][4];
    gemm_tile(a0, sW, b0, true, t, acc);
    __syncthreads();
#pragma unroll
    for (int i = 0; i < 4; ++i)
        *(float4*)&a1[(po * 4 + i) * 68 + oo * 4] = gelu4(acc[i]);
    stage_w(W1, sW, 64, t);
    __syncthreads();
    gemm_tile(a1, sW, b1, false, t, acc);
    __syncthreads();
#pragma unroll
    for (int i = 0; i < 4; ++i)
        *(float4*)&a0[(po * 4 + i) * 68 + oo * 4] = gelu4(acc[i]);
    stage_w(W2, sW, 64, t);
    __syncthreads();
    gemm_tile(a0, sW, b2, false, t, acc);

    const size_t pixbase = (size_t)(b * 256 + h) * 256 + w0;
#pragma unroll
    for (int i = 0; i < 4; ++i) {
        const size_t pix = pixbase + po * 4 + i;
        ushort4 v;
        v.x = f2b(acc[i][0]); v.y = f2b(acc[i][1]);
        v.z = f2b(acc[i][2]); v.w = f2b(acc[i][3]);
        *(ushort4*)&wb_bf[pix * 64 + oo * 4] = v;   // re at oo<8, im at oo>=8 (same offset)
    }
}

// K2: tfw along W. grid = B*H (1024). Reads wb_bf, writes tfwM[b][m][h][c][{re,im}] fp32.
__global__ __launch_bounds__(256) void k_tfw(
    const float* __restrict__ x,
    const unsigned short* __restrict__ wb_bf,
    float* __restrict__ tfwM)
{
    __shared__ float wr[256 * 32];
    __shared__ float wi[256 * 32];
    const int bh = blockIdx.x;
    const int b = bh >> 8, h = bh & 255;
    const int t = threadIdx.x;
    const size_t wboff = (size_t)bh * 16384;
#pragma unroll
    for (int i = 0; i < 8; ++i) {
        const int idx = i * 256 + t;        // 2048 chunks of 8 bf16
        const int px = idx >> 3, f = idx & 7;
        const uint4 raw = *(const uint4*)&wb_bf[wboff + (size_t)px * 64 + f * 8];
        const unsigned short* us = (const unsigned short*)&raw;
        float v[8];
#pragma unroll
        for (int j = 0; j < 8; ++j) v[j] = b2f(us[j]);
        float* dst = (f < 4) ? &wr[px * 32 + f * 8] : &wi[px * 32 + (f - 4) * 8];
        float4 lo; lo.x = v[0]; lo.y = v[1]; lo.z = v[2]; lo.w = v[3];
        float4 hi; hi.x = v[4]; hi.y = v[5]; hi.z = v[6]; hi.w = v[7];
        *(float4*)&dst[0] = lo;
        *(float4*)&dst[4] = hi;
    }
    __syncthreads();
    const int m = t & 31, cg = t >> 5;
    float ar[8], ai[8];
#pragma unroll
    for (int i = 0; i < 8; ++i) { ar[i] = 0.f; ai[i] = 0.f; }
    for (int w4 = 0; w4 < 256; w4 += 4) {
        float4 xv[8];
#pragma unroll
        for (int i = 0; i < 8; ++i)
            xv[i] = *(const float4*)&x[((size_t)(b * 64 + cg * 8 + i) * 256 + h) * 256 + w4];
#pragma unroll
        for (int q = 0; q < 4; ++q) {
            const float wrv = wr[(w4 + q) * 32 + m];
            const float wiv = wi[(w4 + q) * 32 + m];
#pragma unroll
            for (int i = 0; i < 8; ++i) {
                const float xq = (q == 0) ? xv[i].x : (q == 1) ? xv[i].y : (q == 2) ? xv[i].z : xv[i].w;
                ar[i] = fmaf(xq, wrv, ar[i]);
                ai[i] = fmaf(xq, wiv, ai[i]);
            }
        }
    }
    const size_t base = (((size_t)(b * 32 + m) * 256 + h) * 64 + cg * 8) * 2;
#pragma unroll
    for (int p = 0; p < 4; ++p) {
        float4 v;
        v.x = ar[p * 2]; v.y = ai[p * 2]; v.z = ar[p * 2 + 1]; v.w = ai[p * 2 + 1];
        *(float4*)&tfwM[base + p * 4] = v;
    }
}

// K3: hb basis. grid = B*M2*4 (512). Reads tfwM real parts. hb fp32 (B,M2,H,{32re,32im}).
__global__ __launch_bounds__(256) void k_hb_mlp(
    const float* __restrict__ tfwM,
    const float* __restrict__ W0, const float* __restrict__ b0,
    const float* __restrict__ W1, const float* __restrict__ b1,
    const float* __restrict__ W2, const float* __restrict__ b2,
    float* __restrict__ hb_re, float* __restrict__ hb_im)
{
    __shared__ __align__(16) float a0[64 * 68];
    __shared__ __align__(16) float a1[64 * 68];
    __shared__ __align__(16) float sW[65 * 68];
    const int blk = blockIdx.x;
    const int bm = blk >> 2, hq = blk & 3;
    const int h0 = hq * 64;
    const int t = threadIdx.x;
#pragma unroll
    for (int r = 0; r < 4; ++r) {
        const int idx = r * 256 + t;
        const int p = idx >> 4, f = idx & 15;
        const float* src = &tfwM[(size_t)(bm * 256 + h0 + p) * 128 + f * 8];
        const float4 u0 = *(const float4*)&src[0];
        const float4 u1 = *(const float4*)&src[4];
        a0[p * 68 + f * 4 + 0] = u0.x;
        a0[p * 68 + f * 4 + 1] = u0.z;
        a0[p * 68 + f * 4 + 2] = u1.x;
        a0[p * 68 + f * 4 + 3] = u1.z;
    }
    if (t < 64) a0[t * 68 + 64] = (float)(h0 + t) * (2.0f / 255.0f) - 1.0f;
    stage_w(W0, sW, 65, t);
    __syncthreads();

    const int po = t >> 4, oo = t & 15;
    float acc[4][4];
    gemm_tile(a0, sW, b0, true, t, acc);
    __syncthreads();
#pragma unroll
    for (int i = 0; i < 4; ++i)
        *(float4*)&a1[(po * 4 + i) * 68 + oo * 4] = gelu4(acc[i]);
    stage_w(W1, sW, 64, t);
    __syncthreads();
    gemm_tile(a1, sW, b1, false, t, acc);
    __syncthreads();
#pragma unroll
    for (int i = 0; i < 4; ++i)
        *(float4*)&a0[(po * 4 + i) * 68 + oo * 4] = gelu4(acc[i]);
    stage_w(W2, sW, 64, t);
    __syncthreads();
    gemm_tile(a0, sW, b2, false, t, acc);

    const size_t pixbase = (size_t)bm * 256 + h0;
#pragma unroll
    for (int i = 0; i < 4; ++i) {
        const size_t pix = pixbase + po * 4 + i;
        float4 v; v.x = acc[i][0]; v.y = acc[i][1]; v.z = acc[i][2]; v.w = acc[i][3];
        if (oo < 8) *(float4*)&hb_re[pix * 32 + oo * 4] = v;
        else        *(float4*)&hb_im[pix * 32 + (oo - 8) * 4] = v;
    }
}

// K4: tfhw[b,c,k,m] = sum_h tfwM[b,m,h,c] * hb[b,m,h,k]. grid = 256: (bm,chalf).
__global__ __launch_bounds__(256) void k_tfhw2(
    const float* __restrict__ tfwM,
    const float* __restrict__ hb_re, const float* __restrict__ hb_im,
    float* __restrict__ tfhw_re, float* __restrict__ tfhw_im)
{
    __shared__ float hr[256 * 32];
    __shared__ float hi2[256 * 32];
    __shared__ float slab[32 * 64];
    const int blk = blockIdx.x;
    const int bm = blk >> 1, chalf = blk & 1;
    const int b = bm >> 5, m = bm & 31;
    const int t = threadIdx.x;
    const size_t hboff = (size_t)bm * 8192;
#pragma unroll
    for (int i = 0; i < 8; ++i) {
        const int idx = i * 256 + t;
        *(float4*)&hr[idx * 4] = *(const float4*)&hb_re[hboff + (size_t)idx * 4];
        *(float4*)&hi2[idx * 4] = *(const float4*)&hb_im[hboff + (size_t)idx * 4];
    }
    const int k = t & 31, cq = t >> 5;
    float accr[4] = {0.f, 0.f, 0.f, 0.f}, acci[4] = {0.f, 0.f, 0.f, 0.f};
    const size_t tbase = (size_t)bm * 256 * 128;
    for (int ht = 0; ht < 8; ++ht) {
        __syncthreads();
#pragma unroll
        for (int r = 0; r < 2; ++r) {
            const int q = r * 256 + t;
            const int hl = q >> 3, f = q & 7;
            *(float4*)&slab[hl * 64 + f * 4] =
                *(const float4*)&tfwM[tbase + (size_t)(ht * 32 + hl) * 128 + chalf * 64 + f * 4];
        }
        __syncthreads();
#pragma unroll 8
        for (int hl = 0; hl < 32; ++hl) {
            const int h = ht * 32 + hl;
            const float hrv = hr[h * 32 + k];
            const float hiv = hi2[h * 32 + k];
            const float4 u0 = *(const float4*)&slab[hl * 64 + cq * 8];
            const float4 u1 = *(const float4*)&slab[hl * 64 + cq * 8 + 4];
            accr[0] = fmaf(u0.x, hrv, fmaf(-u0.y, hiv, accr[0]));
            acci[0] = fmaf(u0.x, hiv, fmaf( u0.y, hrv, acci[0]));
            accr[1] = fmaf(u0.z, hrv, fmaf(-u0.w, hiv, accr[1]));
            acci[1] = fmaf(u0.z, hiv, fmaf( u0.w, hrv, acci[1]));
            accr[2] = fmaf(u1.x, hrv, fmaf(-u1.y, hiv, accr[2]));
            acci[2] = fmaf(u1.x, hiv, fmaf( u1.y, hrv, acci[2]));
            accr[3] = fmaf(u1.z, hrv, fmaf(-u1.w, hiv, accr[3]));
            acci[3] = fmaf(u1.z, hiv, fmaf( u1.w, hrv, acci[3]));
        }
    }
#pragma unroll
    for (int i = 0; i < 4; ++i) {
        const int c = chalf * 32 + cq * 4 + i;
        const size_t po = ((size_t)(b * 64 + c) * 32 + k) * 32 + m;
        tfhw_re[po] = accr[i];
        tfhw_im[po] = acci[i];
    }
}

// K5: proc[b,o,k,m] = sum_c tfhw[b,c,k,m] * Wf[c,o,k,m]. grid = 256.
__global__ __launch_bounds__(256) void k_proc(
    const float* __restrict__ tfhw_re, const float* __restrict__ tfhw_im,
    const float* __restrict__ Wf_re, const float* __restrict__ Wf_im,
    float* __restrict__ proc_re, float* __restrict__ proc_im)
{
    const int o = blockIdx.x >> 2, kq = blockIdx.x & 3;
    const int t = threadIdx.x;
    const int mo = kq * 256 + t;
    float accr[4] = {0.f, 0.f, 0.f, 0.f}, acci[4] = {0.f, 0.f, 0.f, 0.f};
    for (int c = 0; c < 64; ++c) {
        const float wfr = Wf_re[(size_t)(c * 64 + o) * 1024 + mo];
        const float wfi = Wf_im[(size_t)(c * 64 + o) * 1024 + mo];
#pragma unroll
        for (int bb = 0; bb < 4; ++bb) {
            const float tr = tfhw_re[(size_t)(bb * 64 + c) * 1024 + mo];
            const float ti = tfhw_im[(size_t)(bb * 64 + c) * 1024 + mo];
            accr[bb] = fmaf(tr, wfr, fmaf(-ti, wfi, accr[bb]));
            acci[bb] = fmaf(tr, wfi, fmaf(ti, wfr, acci[bb]));
        }
    }
#pragma unroll
    for (int bb = 0; bb < 4; ++bb) {
        proc_re[(size_t)(bb * 64 + o) * 1024 + mo] = accr[bb];
        proc_im[(size_t)(bb * 64 + o) * 1024 + mo] = acci[bb];
    }
}

// K6: recO[b,h][o][64k] bf16: k<32 -> Re at m=k, k>=32 -> Im at m=k-32.
// grid = 512: (b,m,hq). block: (o=t&63, hg=t>>6), 16 h each.
__global__ __launch_bounds__(256) void k_rec2(
    const float* __restrict__ proc_re, const float* __restrict__ proc_im,
    const float* __restrict__ hb_re, const float* __restrict__ hb_im,
    unsigned short* __restrict__ recO)
{
    __shared__ float lhr[64 * 32];
    __shared__ float lhi[64 * 32];
    const int blk = blockIdx.x;
    const int bm = blk >> 2, hq = blk & 3;
    const int b = bm >> 5, m = bm & 31;
    const int t = threadIdx.x;
#pragma unroll
    for (int r = 0; r < 2; ++r) {
        const int q = r * 256 + t;
        const int hl = q >> 3, f = q & 7;
        const size_t src = (size_t)bm * 8192 + (size_t)(hq * 64 + hl) * 32 + f * 4;
        *(float4*)&lhr[hl * 32 + f * 4] = *(const float4*)&hb_re[src];
        *(float4*)&lhi[hl * 32 + f * 4] = *(const float4*)&hb_im[src];
    }
    const int o = t & 63, hg = t >> 6;
    float Pr[32], Pi[32];
#pragma unroll
    for (int k = 0; k < 32; ++k) {
        const size_t pa = ((size_t)(b * 64 + o) * 32 + k) * 32 + m;
        Pr[k] = proc_re[pa];
        Pi[k] = proc_im[pa];
    }
    __syncthreads();
    for (int hh = 0; hh < 16; ++hh) {
        const int hl = hg * 16 + hh;
        float ar = 0.f, ai = 0.f;
#pragma unroll
        for (int k = 0; k < 32; ++k) {
            const float hrv = lhr[hl * 32 + k], hiv = lhi[hl * 32 + k];
            ar = fmaf(Pr[k], hrv, fmaf(Pi[k], hiv, ar));
            ai = fmaf(Pi[k], hrv, fmaf(-Pr[k], hiv, ai));
        }
        const int h = hq * 64 + hl;
        const size_t rb = ((size_t)(b * 256 + h) * 64 + o) * 64;
        recO[rb + m]      = f2b(ar);
        recO[rb + 32 + m] = f2b(ai);
    }
}

// K7: MFMA fused final: spatial = wb . recO^T, mixer, skip, gelus.
// Computes transposed GEMMs C^T = A_rowmajor x B_fragfrom[px][k] per derivation.
// grid = B*H*4 (4096): (b,h,wq). 64 px/block, 4 waves.
__global__ __launch_bounds__(256) void k_final4(
    const float* __restrict__ x,
    const unsigned short* __restrict__ wb_bf,
    const unsigned short* __restrict__ recO,
    const float* __restrict__ mw, const float* __restrict__ mb,
    const float* __restrict__ scw, const float* __restrict__ scb,
    float* __restrict__ out)
{
    constexpr int LD = 72;                         // bf16 row stride (144B, 16B-aligned)
    __shared__ __align__(16) unsigned short sWb[64 * LD];  // [px][k]: wb; later mw [o][c]
    __shared__ __align__(16) unsigned short sR [64 * LD];  // [o][k]: recO; later scw [o][c]
    __shared__ __align__(16) unsigned short sX [64 * LD];  // [px][c]: x^T
    __shared__ __align__(16) unsigned short sS [64 * LD];  // [px][c]: spatial
    const int blk = blockIdx.x;
    const int b = blk >> 10, h = (blk >> 2) & 255, wq = blk & 3;
    const int w0 = wq * 64;
    const int t = threadIdx.x;
    const int lane = t & 63, wv = t >> 6;
    const size_t pixbase = (size_t)(b * 256 + h) * 256 + w0;

    // stage wb rows (bf16, coalesced 16B)
#pragma unroll
    for (int r = 0; r < 2; ++r) {
        const int idx = r * 256 + t;
        const int px = idx >> 3, f = idx & 7;
        *(uint4*)&sWb[px * LD + f * 8] = *(const uint4*)&wb_bf[(pixbase + px) * 64 + f * 8];
    }
    // stage recO rows
    const size_t recbase = (size_t)(b * 256 + h) * 4096;
#pragma unroll
    for (int r = 0; r < 2; ++r) {
        const int idx = r * 256 + t;
        const int o = idx >> 3, f = idx & 7;
        *(uint4*)&sR[o * LD + f * 8] = *(const uint4*)&recO[recbase + (size_t)o * 64 + f * 8];
    }
    // stage x transposed -> sX[px][c] bf16
#pragma unroll
    for (int r = 0; r < 4; ++r) {
        const int idx = r * 256 + t;
        const int c = idx >> 4, wg = idx & 15;
        const float4 v = *(const float4*)&x[((size_t)(b * 64 + c) * 256 + h) * 256 + w0 + wg * 4];
        sX[(wg * 4 + 0) * LD + c] = f2b(v.x);
        sX[(wg * 4 + 1) * LD + c] = f2b(v.y);
        sX[(wg * 4 + 2) * LD + c] = f2b(v.z);
        sX[(wg * 4 + 3) * LD + c] = f2b(v.w);
    }
    __syncthreads();

    const int arow = lane & 15;
    const int koff = (lane >> 4) * 8;
    const f32x4 zero = {0.f, 0.f, 0.f, 0.f};

    // Phase A: spatialT[o][px] = sum_k recO[o][k] * wb[px][k]
    f32x4 accA[4] = {zero, zero, zero, zero};
#pragma unroll
    for (int kc = 0; kc < 2; ++kc) {
        const bf16x8 a = *(const bf16x8*)&sR[(16 * wv + arow) * LD + kc * 32 + koff];
#pragma unroll
        for (int nt = 0; nt < 4; ++nt) {
            const bf16x8 bb = *(const bf16x8*)&sWb[(nt * 16 + arow) * LD + kc * 32 + koff];
            accA[nt] = __builtin_amdgcn_mfma_f32_16x16x32_bf16(a, bb, accA[nt], 0, 0, 0);
        }
    }
    __syncthreads();   // done reading sWb/sR; sS not yet read

    // scatter spatial -> sS[px][c]  (c = row of accA)
    const int crow = 16 * wv + (lane >> 4) * 4;
#pragma unroll
    for (int nt = 0; nt < 4; ++nt) {
        const int px = nt * 16 + arow;
#pragma unroll
        for (int j = 0; j < 4; ++j)
            sS[px * LD + crow + j] = f2b(accA[nt][j] * (1.0f / 65536.0f));
    }
    // stage mw -> sWb, scw -> sR (bf16)
#pragma unroll
    for (int r = 0; r < 4; ++r) {
        const int idx = r * 256 + t;
        const int o = idx >> 4, cq = idx & 15;
        const float4 v1 = *(const float4*)&mw[o * 64 + cq * 4];
        ushort4 u1;
        u1.x = f2b(v1.x); u1.y = f2b(v1.y); u1.z = f2b(v1.z); u1.w = f2b(v1.w);
        *(ushort4*)&sWb[o * LD + cq * 4] = u1;
        const float4 v2 = *(const float4*)&scw[o * 64 + cq * 4];
        ushort4 u2;
        u2.x = f2b(v2.x); u2.y = f2b(v2.y); u2.z = f2b(v2.z); u2.w = f2b(v2.w);
        *(ushort4*)&sR[o * LD + cq * 4] = u2;
    }
    __syncthreads();

    // Phase B: mixT[o][px] = sum_c mw[o][c] * spatial[px][c]
    // Phase C: skipT[o][px] = sum_c scw[o][c] * x^T[px][c]
    f32x4 accB[4] = {zero, zero, zero, zero};
    f32x4 accC[4] = {zero, zero, zero, zero};
#pragma unroll
    for (int kc = 0; kc < 2; ++kc) {
        const bf16x8 am = *(const bf16x8*)&sWb[(16 * wv + arow) * LD + kc * 32 + koff];
        const bf16x8 as = *(const bf16x8*)&sR [(16 * wv + arow) * LD + kc * 32 + koff];
#pragma unroll
        for (int nt = 0; nt < 4; ++nt) {
            const bf16x8 bs = *(const bf16x8*)&sS[(nt * 16 + arow) * LD + kc * 32 + koff];
            const bf16x8 bx = *(const bf16x8*)&sX[(nt * 16 + arow) * LD + kc * 32 + koff];
            accB[nt] = __builtin_amdgcn_mfma_f32_16x16x32_bf16(am, bs, accB[nt], 0, 0, 0);
            accC[nt] = __builtin_amdgcn_mfma_f32_16x16x32_bf16(as, bx, accC[nt], 0, 0, 0);
        }
    }

    // epilogue: gelu(gelu(mix + mb) + skip + scb), store
#pragma unroll
    for (int nt = 0; nt < 4; ++nt) {
        const int px = nt * 16 + arow;
#pragma unroll
        for (int j = 0; j < 4; ++j) {
            const int o = crow + j;
            const float y = gelu_f(accB[nt][j] + mb[o]);
            const float z = y + accC[nt][j] + scb[o];
            out[((size_t)(b * 64 + o) * 256 + h) * 256 + w0 + px] = gelu_f(z);
        }
    }
}

extern "C" void kernel_launch(void* const* d_in, const int* in_sizes, int n_in,
                              void* d_out, int out_size, void* d_ws, size_t ws_size,
                              hipStream_t stream) {
    const float* x    = (const float*)d_in[0];
    const float* wW0  = (const float*)d_in[1];
    const float* wb0  = (const float*)d_in[2];
    const float* wW1  = (const float*)d_in[3];
    const float* wb1  = (const float*)d_in[4];
    const float* wW2  = (const float*)d_in[5];
    const float* wb2  = (const float*)d_in[6];
    const float* hW0  = (const float*)d_in[7];
    const float* hb0  = (const float*)d_in[8];
    const float* hW1  = (const float*)d_in[9];
    const float* hb1  = (const float*)d_in[10];
    const float* hW2  = (const float*)d_in[11];
    const float* hb2  = (const float*)d_in[12];
    const float* Wf_re = (const float*)d_in[13];
    const float* Wf_im = (const float*)d_in[14];
    const float* mw   = (const float*)d_in[15];
    const float* mbv  = (const float*)d_in[16];
    const float* scw  = (const float*)d_in[17];
    const float* scb  = (const float*)d_in[18];

    char* base = (char*)d_ws;
    unsigned short* wb_bf = (unsigned short*)base;                 // 33,554,432 B
    float* tfwM    = (float*)(base + 33554432);                    // 16,777,216 B
    float* hb_re   = (float*)(base + 33554432 + 16777216);         //  4,194,304 B
    float* hb_im   = (float*)(base + 33554432 + 16777216 + 4194304);
    float* tfhw_re = (float*)(base + 33554432 + 16777216 + 8388608);
    float* tfhw_im = (float*)(base + 33554432 + 16777216 + 8388608 + 1048576);
    float* proc_re = (float*)(base + 33554432 + 16777216 + 8388608 + 2097152);
    float* proc_im = (float*)(base + 33554432 + 16777216 + 8388608 + 3145728);
    unsigned short* recO = (unsigned short*)(base + 33554432 + 16777216 + 8388608 + 4194304);
    // total ~71 MB

    k_wb_mlp<<<4096, 256, 0, stream>>>(x, wW0, wb0, wW1, wb1, wW2, wb2, wb_bf);
    k_tfw<<<1024, 256, 0, stream>>>(x, wb_bf, tfwM);
    k_hb_mlp<<<512, 256, 0, stream>>>(tfwM, hW0, hb0, hW1, hb1, hW2, hb2, hb_re, hb_im);
    k_tfhw2<<<256, 256, 0, stream>>>(tfwM, hb_re, hb_im, tfhw_re, tfhw_im);
    k_proc<<<256, 256, 0, stream>>>(tfhw_re, tfhw_im, Wf_re, Wf_im, proc_re, proc_im);
    k_rec2<<<512, 256, 0, stream>>>(proc_re, proc_im, hb_re, hb_im, recO);
    k_final4<<<4096, 256, 0, stream>>>(x, wb_bf, recO, mw, mbv, scw, scb, (float*)d_out);
}

// Round 5
// 284.998 us; speedup vs baseline: 4.1150x; 1.3171x over previous
//
#include <hip/hip_runtime.h>
#include <math.h>

// B=4, C=64, OUT=64, H=256, W=256, M1=32, M2=32, HID=64, COORD=65

typedef __attribute__((ext_vector_type(8))) short bf16x8;
typedef __attribute__((ext_vector_type(4))) float f32x4;

__device__ __forceinline__ float gelu_f(float v) {
    return 0.5f * v * (1.0f + erff(v * 0.70710678118654752440f));
}

__device__ __forceinline__ unsigned short f2b(float f) {
    union { float f; unsigned int u; } v; v.f = f;
    unsigned int u = v.u + 0x7FFFu + ((v.u >> 16) & 1u);   // RNE
    return (unsigned short)(u >> 16);
}
__device__ __forceinline__ float b2f(unsigned short b) {
    union { unsigned int u; float f; } v; v.u = ((unsigned int)b) << 16;
    return v.f;
}

// ---------------------------------------------------------------------------
// K_prep: transpose + bf16-convert MLP weights. wT[o][k] = W[k][o].
// Layer-0 matrices padded to K=96 with zeros (act pad is also zeroed -> no NaN).
// ---------------------------------------------------------------------------
__global__ void k_prep(const float* __restrict__ wW0, const float* __restrict__ wW1,
                       const float* __restrict__ wW2,
                       const float* __restrict__ hW0, const float* __restrict__ hW1,
                       const float* __restrict__ hW2,
                       unsigned short* __restrict__ wT0, unsigned short* __restrict__ wT1,
                       unsigned short* __restrict__ wT2,
                       unsigned short* __restrict__ hT0, unsigned short* __restrict__ hT1,
                       unsigned short* __restrict__ hT2)
{
    const int t = threadIdx.x;
    for (int idx = t; idx < 64 * 96; idx += 256) {
        const int o = idx / 96, k = idx % 96;
        wT0[idx] = (k < 65) ? f2b(wW0[k * 64 + o]) : (unsigned short)0;
        hT0[idx] = (k < 65) ? f2b(hW0[k * 64 + o]) : (unsigned short)0;
    }
    for (int idx = t; idx < 4096; idx += 256) {
        const int o = idx >> 6, k = idx & 63;
        wT1[idx] = f2b(wW1[k * 64 + o]);
        wT2[idx] = f2b(wW2[k * 64 + o]);
        hT1[idx] = f2b(hW1[k * 64 + o]);
        hT2[idx] = f2b(hW2[k * 64 + o]);
    }
}

// ---------------------------------------------------------------------------
// MFMA MLP layer: D[o][px] = sum_k sW[o][k] * sAct[px][k] (+bias, opt gelu),
// scatter bf16 to dst[px][o]. 4 waves; wave wv owns o-strip 16*wv.
// ---------------------------------------------------------------------------
constexpr int MLD = 104;   // bf16 row stride (208 B): 2-way max bank aliasing

template<bool GELU, int NKC>
__device__ __forceinline__ void mfma_layer(
    const unsigned short* __restrict__ sW,
    const unsigned short* __restrict__ sAct,
    unsigned short* __restrict__ dst,
    const float* __restrict__ bias, int lane, int wv)
{
    const int arow = lane & 15;
    const int koff = (lane >> 4) * 8;
    const int crow = 16 * wv + (lane >> 4) * 4;
    const f32x4 zero = {0.f, 0.f, 0.f, 0.f};
    f32x4 acc[4] = {zero, zero, zero, zero};
#pragma unroll
    for (int kc = 0; kc < NKC; ++kc) {
        const bf16x8 a = *(const bf16x8*)&sW[(16 * wv + arow) * MLD + kc * 32 + koff];
#pragma unroll
        for (int nt = 0; nt < 4; ++nt) {
            const bf16x8 b = *(const bf16x8*)&sAct[(nt * 16 + arow) * MLD + kc * 32 + koff];
            acc[nt] = __builtin_amdgcn_mfma_f32_16x16x32_bf16(a, b, acc[nt], 0, 0, 0);
        }
    }
    const float4 bv = *(const float4*)&bias[crow];
#pragma unroll
    for (int nt = 0; nt < 4; ++nt) {
        const int px = nt * 16 + arow;
        float v0 = acc[nt][0] + bv.x;
        float v1 = acc[nt][1] + bv.y;
        float v2 = acc[nt][2] + bv.z;
        float v3 = acc[nt][3] + bv.w;
        if (GELU) { v0 = gelu_f(v0); v1 = gelu_f(v1); v2 = gelu_f(v2); v3 = gelu_f(v3); }
        ushort4 u;
        u.x = f2b(v0); u.y = f2b(v1); u.z = f2b(v2); u.w = f2b(v3);
        *(ushort4*)&dst[px * MLD + crow] = u;
    }
}

__device__ __forceinline__ void stage_wT96(const unsigned short* __restrict__ src,
                                           unsigned short* __restrict__ sW, int t) {
    // 64 rows x 96 bf16 = 768 uint4
#pragma unroll
    for (int r = 0; r < 3; ++r) {
        const int idx = r * 256 + t;
        const int row = idx / 12, f = idx % 12;
        *(uint4*)&sW[row * MLD + f * 8] = *(const uint4*)&src[row * 96 + f * 8];
    }
}
__device__ __forceinline__ void stage_wT64(const unsigned short* __restrict__ src,
                                           unsigned short* __restrict__ sW, int t) {
    // 64 rows x 64 bf16 = 512 uint4
#pragma unroll
    for (int r = 0; r < 2; ++r) {
        const int idx = r * 256 + t;
        const int row = idx >> 3, f = idx & 7;
        *(uint4*)&sW[row * MLD + f * 8] = *(const uint4*)&src[row * 64 + f * 8];
    }
}

// K1: wb basis via MFMA. grid = B*H*4 (4096): (b,h,wq). out wb_bf[pix][64] (32re|32im).
__global__ __launch_bounds__(256) void k_wb_mlp2(
    const float* __restrict__ x,
    const unsigned short* __restrict__ wT0, const float* __restrict__ b0,
    const unsigned short* __restrict__ wT1, const float* __restrict__ b1,
    const unsigned short* __restrict__ wT2, const float* __restrict__ b2,
    unsigned short* __restrict__ wb_bf)
{
    __shared__ __align__(16) unsigned short sA[64 * MLD];
    __shared__ __align__(16) unsigned short sB[64 * MLD];
    __shared__ __align__(16) unsigned short sW[64 * MLD];
    const int blk = blockIdx.x;
    const int b = blk >> 10, h = (blk >> 2) & 255, wq = blk & 3;
    const int w0 = wq * 64;
    const int t = threadIdx.x;
    const int lane = t & 63, wv = t >> 6;

    // stage x^T -> sA[px][c] bf16
#pragma unroll
    for (int r = 0; r < 4; ++r) {
        const int idx = r * 256 + t;
        const int c = idx >> 4, wg = idx & 15;
        const float4 v = *(const float4*)&x[((size_t)(b * 64 + c) * 256 + h) * 256 + w0 + wg * 4];
        sA[(wg * 4 + 0) * MLD + c] = f2b(v.x);
        sA[(wg * 4 + 1) * MLD + c] = f2b(v.y);
        sA[(wg * 4 + 2) * MLD + c] = f2b(v.z);
        sA[(wg * 4 + 3) * MLD + c] = f2b(v.w);
    }
    if (t < 64) {
#pragma unroll
        for (int i = 1; i < 32; ++i) sA[t * MLD + 64 + i] = 0;
        sA[t * MLD + 64] = f2b((float)(w0 + t) * (2.0f / 255.0f) - 1.0f);
    }
    stage_wT96(wT0, sW, t);
    __syncthreads();
    mfma_layer<true, 3>(sW, sA, sB, b0, lane, wv);
    __syncthreads();
    stage_wT64(wT1, sW, t);
    __syncthreads();
    mfma_layer<true, 2>(sW, sB, sA, b1, lane, wv);
    __syncthreads();
    stage_wT64(wT2, sW, t);
    __syncthreads();
    mfma_layer<false, 2>(sW, sA, sB, b2, lane, wv);
    __syncthreads();

    // coalesced write-out from sB[px][o]
    const size_t pixbase = (size_t)(b * 256 + h) * 256 + w0;
#pragma unroll
    for (int r = 0; r < 2; ++r) {
        const int idx = r * 256 + t;
        const int px = idx >> 3, f = idx & 7;
        *(uint4*)&wb_bf[(pixbase + px) * 64 + f * 8] = *(const uint4*)&sB[px * MLD + f * 8];
    }
}

// K3: hb basis via MFMA. grid = B*M2*4 (512): (bm,hq). out hb_bf[pix][64].
__global__ __launch_bounds__(256) void k_hb_mlp2(
    const float* __restrict__ tfwM,
    const unsigned short* __restrict__ hT0, const float* __restrict__ b0,
    const unsigned short* __restrict__ hT1, const float* __restrict__ b1,
    const unsigned short* __restrict__ hT2, const float* __restrict__ b2,
    unsigned short* __restrict__ hb_bf)
{
    __shared__ __align__(16) unsigned short sA[64 * MLD];
    __shared__ __align__(16) unsigned short sB[64 * MLD];
    __shared__ __align__(16) unsigned short sW[64 * MLD];
    const int blk = blockIdx.x;
    const int bm = blk >> 2, hq = blk & 3;
    const int h0 = hq * 64;
    const int t = threadIdx.x;
    const int lane = t & 63, wv = t >> 6;

    // stage tfw real parts -> sA[p][c] bf16
#pragma unroll
    for (int r = 0; r < 4; ++r) {
        const int idx = r * 256 + t;
        const int p = idx >> 4, f = idx & 15;
        const float* src = &tfwM[(size_t)(bm * 256 + h0 + p) * 128 + f * 8];
        const float4 u0 = *(const float4*)&src[0];
        const float4 u1 = *(const float4*)&src[4];
        ushort4 u;
        u.x = f2b(u0.x); u.y = f2b(u0.z); u.z = f2b(u1.x); u.w = f2b(u1.z);
        *(ushort4*)&sA[p * MLD + f * 4] = u;
    }
    if (t < 64) {
#pragma unroll
        for (int i = 1; i < 32; ++i) sA[t * MLD + 64 + i] = 0;
        sA[t * MLD + 64] = f2b((float)(h0 + t) * (2.0f / 255.0f) - 1.0f);
    }
    stage_wT96(hT0, sW, t);
    __syncthreads();
    mfma_layer<true, 3>(sW, sA, sB, b0, lane, wv);
    __syncthreads();
    stage_wT64(hT1, sW, t);
    __syncthreads();
    mfma_layer<true, 2>(sW, sB, sA, b1, lane, wv);
    __syncthreads();
    stage_wT64(hT2, sW, t);
    __syncthreads();
    mfma_layer<false, 2>(sW, sA, sB, b2, lane, wv);
    __syncthreads();

    const size_t pixbase = (size_t)bm * 256 + h0;
#pragma unroll
    for (int r = 0; r < 2; ++r) {
        const int idx = r * 256 + t;
        const int px = idx >> 3, f = idx & 7;
        *(uint4*)&hb_bf[(pixbase + px) * 64 + f * 8] = *(const uint4*)&sB[px * MLD + f * 8];
    }
}

// K2: tfw along W. grid = B*H (1024). Reads wb_bf, writes tfwM[b][m][h][c][{re,im}] fp32.
__global__ __launch_bounds__(256) void k_tfw(
    const float* __restrict__ x,
    const unsigned short* __restrict__ wb_bf,
    float* __restrict__ tfwM)
{
    __shared__ float wr[256 * 32];
    __shared__ float wi[256 * 32];
    const int bh = blockIdx.x;
    const int b = bh >> 8, h = bh & 255;
    const int t = threadIdx.x;
    const size_t wboff = (size_t)bh * 16384;
#pragma unroll
    for (int i = 0; i < 8; ++i) {
        const int idx = i * 256 + t;
        const int px = idx >> 3, f = idx & 7;
        const uint4 raw = *(const uint4*)&wb_bf[wboff + (size_t)px * 64 + f * 8];
        const unsigned short* us = (const unsigned short*)&raw;
        float v[8];
#pragma unroll
        for (int j = 0; j < 8; ++j) v[j] = b2f(us[j]);
        float* dst = (f < 4) ? &wr[px * 32 + f * 8] : &wi[px * 32 + (f - 4) * 8];
        float4 lo; lo.x = v[0]; lo.y = v[1]; lo.z = v[2]; lo.w = v[3];
        float4 hi; hi.x = v[4]; hi.y = v[5]; hi.z = v[6]; hi.w = v[7];
        *(float4*)&dst[0] = lo;
        *(float4*)&dst[4] = hi;
    }
    __syncthreads();
    const int m = t & 31, cg = t >> 5;
    float ar[8], ai[8];
#pragma unroll
    for (int i = 0; i < 8; ++i) { ar[i] = 0.f; ai[i] = 0.f; }
    for (int w4 = 0; w4 < 256; w4 += 4) {
        float4 xv[8];
#pragma unroll
        for (int i = 0; i < 8; ++i)
            xv[i] = *(const float4*)&x[((size_t)(b * 64 + cg * 8 + i) * 256 + h) * 256 + w4];
#pragma unroll
        for (int q = 0; q < 4; ++q) {
            const float wrv = wr[(w4 + q) * 32 + m];
            const float wiv = wi[(w4 + q) * 32 + m];
#pragma unroll
            for (int i = 0; i < 8; ++i) {
                const float xq = (q == 0) ? xv[i].x : (q == 1) ? xv[i].y : (q == 2) ? xv[i].z : xv[i].w;
                ar[i] = fmaf(xq, wrv, ar[i]);
                ai[i] = fmaf(xq, wiv, ai[i]);
            }
        }
    }
    const size_t base = (((size_t)(b * 32 + m) * 256 + h) * 64 + cg * 8) * 2;
#pragma unroll
    for (int p = 0; p < 4; ++p) {
        float4 v;
        v.x = ar[p * 2]; v.y = ai[p * 2]; v.z = ar[p * 2 + 1]; v.w = ai[p * 2 + 1];
        *(float4*)&tfwM[base + p * 4] = v;
    }
}

// K4: tfhw[b,c,k,m] = sum_h tfwM[b,m,h,c] * hb[b,m,h,k]. grid = 256: (bm,chalf).
__global__ __launch_bounds__(256) void k_tfhw2(
    const float* __restrict__ tfwM,
    const unsigned short* __restrict__ hb_bf,
    float* __restrict__ tfhw_re, float* __restrict__ tfhw_im)
{
    __shared__ float hr[256 * 32];
    __shared__ float hi2[256 * 32];
    __shared__ float slab[32 * 64];
    const int blk = blockIdx.x;
    const int bm = blk >> 1, chalf = blk & 1;
    const int b = bm >> 5, m = bm & 31;
    const int t = threadIdx.x;
    const size_t hbase = (size_t)bm * 256;
#pragma unroll
    for (int i = 0; i < 8; ++i) {
        const int idx = i * 256 + t;
        const int px = idx >> 3, f = idx & 7;
        const uint4 raw = *(const uint4*)&hb_bf[(hbase + px) * 64 + f * 8];
        const unsigned short* us = (const unsigned short*)&raw;
        float v[8];
#pragma unroll
        for (int j = 0; j < 8; ++j) v[j] = b2f(us[j]);
        float* dst = (f < 4) ? &hr[px * 32 + f * 8] : &hi2[px * 32 + (f - 4) * 8];
        float4 lo; lo.x = v[0]; lo.y = v[1]; lo.z = v[2]; lo.w = v[3];
        float4 hi; hi.x = v[4]; hi.y = v[5]; hi.z = v[6]; hi.w = v[7];
        *(float4*)&dst[0] = lo;
        *(float4*)&dst[4] = hi;
    }
    const int k = t & 31, cq = t >> 5;
    float accr[4] = {0.f, 0.f, 0.f, 0.f}, acci[4] = {0.f, 0.f, 0.f, 0.f};
    const size_t tbase = (size_t)bm * 256 * 128;
    for (int ht = 0; ht < 8; ++ht) {
        __syncthreads();
#pragma unroll
        for (int r = 0; r < 2; ++r) {
            const int q = r * 256 + t;
            const int hl = q >> 3, f = q & 7;
            *(float4*)&slab[hl * 64 + f * 4] =
                *(const float4*)&tfwM[tbase + (size_t)(ht * 32 + hl) * 128 + chalf * 64 + f * 4];
        }
        __syncthreads();
#pragma unroll 8
        for (int hl = 0; hl < 32; ++hl) {
            const int h = ht * 32 + hl;
            const float hrv = hr[h * 32 + k];
            const float hiv = hi2[h * 32 + k];
            const float4 u0 = *(const float4*)&slab[hl * 64 + cq * 8];
            const float4 u1 = *(const float4*)&slab[hl * 64 + cq * 8 + 4];
            accr[0] = fmaf(u0.x, hrv, fmaf(-u0.y, hiv, accr[0]));
            acci[0] = fmaf(u0.x, hiv, fmaf( u0.y, hrv, acci[0]));
            accr[1] = fmaf(u0.z, hrv, fmaf(-u0.w, hiv, accr[1]));
            acci[1] = fmaf(u0.z, hiv, fmaf( u0.w, hrv, acci[1]));
            accr[2] = fmaf(u1.x, hrv, fmaf(-u1.y, hiv, accr[2]));
            acci[2] = fmaf(u1.x, hiv, fmaf( u1.y, hrv, acci[2]));
            accr[3] = fmaf(u1.z, hrv, fmaf(-u1.w, hiv, accr[3]));
            acci[3] = fmaf(u1.z, hiv, fmaf( u1.w, hrv, acci[3]));
        }
    }
#pragma unroll
    for (int i = 0; i < 4; ++i) {
        const int c = chalf * 32 + cq * 4 + i;
        const size_t po = ((size_t)(b * 64 + c) * 32 + k) * 32 + m;
        tfhw_re[po] = accr[i];
        tfhw_im[po] = acci[i];
    }
}

// K5: proc[b,o,k,m] = sum_c tfhw[b,c,k,m] * Wf[c,o,k,m]. grid = 256.
__global__ __launch_bounds__(256) void k_proc(
    const float* __restrict__ tfhw_re, const float* __restrict__ tfhw_im,
    const float* __restrict__ Wf_re, const float* __restrict__ Wf_im,
    float* __restrict__ proc_re, float* __restrict__ proc_im)
{
    const int o = blockIdx.x >> 2, kq = blockIdx.x & 3;
    const int t = threadIdx.x;
    const int mo = kq * 256 + t;
    float accr[4] = {0.f, 0.f, 0.f, 0.f}, acci[4] = {0.f, 0.f, 0.f, 0.f};
    for (int c = 0; c < 64; ++c) {
        const float wfr = Wf_re[(size_t)(c * 64 + o) * 1024 + mo];
        const float wfi = Wf_im[(size_t)(c * 64 + o) * 1024 + mo];
#pragma unroll
        for (int bb = 0; bb < 4; ++bb) {
            const float tr = tfhw_re[(size_t)(bb * 64 + c) * 1024 + mo];
            const float ti = tfhw_im[(size_t)(bb * 64 + c) * 1024 + mo];
            accr[bb] = fmaf(tr, wfr, fmaf(-ti, wfi, accr[bb]));
            acci[bb] = fmaf(tr, wfi, fmaf(ti, wfr, acci[bb]));
        }
    }
#pragma unroll
    for (int bb = 0; bb < 4; ++bb) {
        proc_re[(size_t)(bb * 64 + o) * 1024 + mo] = accr[bb];
        proc_im[(size_t)(bb * 64 + o) * 1024 + mo] = acci[bb];
    }
}

// K6: recO[b,h][o][64] bf16: col k<32 -> Re at m=k, k>=32 -> Im at m=k-32.
__global__ __launch_bounds__(256) void k_rec2(
    const float* __restrict__ proc_re, const float* __restrict__ proc_im,
    const unsigned short* __restrict__ hb_bf,
    unsigned short* __restrict__ recO)
{
    __shared__ float lhr[64 * 32];
    __shared__ float lhi[64 * 32];
    const int blk = blockIdx.x;
    const int bm = blk >> 2, hq = blk & 3;
    const int b = bm >> 5, m = bm & 31;
    const int t = threadIdx.x;
#pragma unroll
    for (int r = 0; r < 2; ++r) {
        const int q = r * 256 + t;
        const int hl = q >> 3, f = q & 7;
        const uint4 raw = *(const uint4*)&hb_bf[((size_t)bm * 256 + hq * 64 + hl) * 64 + f * 8];
        const unsigned short* us = (const unsigned short*)&raw;
        float v[8];
#pragma unroll
        for (int j = 0; j < 8; ++j) v[j] = b2f(us[j]);
        float* dst = (f < 4) ? &lhr[hl * 32 + f * 8] : &lhi[hl * 32 + (f - 4) * 8];
        float4 lo; lo.x = v[0]; lo.y = v[1]; lo.z = v[2]; lo.w = v[3];
        float4 hi; hi.x = v[4]; hi.y = v[5]; hi.z = v[6]; hi.w = v[7];
        *(float4*)&dst[0] = lo;
        *(float4*)&dst[4] = hi;
    }
    const int o = t & 63, hg = t >> 6;
    float Pr[32], Pi[32];
#pragma unroll
    for (int k = 0; k < 32; ++k) {
        const size_t pa = ((size_t)(b * 64 + o) * 32 + k) * 32 + m;
        Pr[k] = proc_re[pa];
        Pi[k] = proc_im[pa];
    }
    __syncthreads();
    for (int hh = 0; hh < 16; ++hh) {
        const int hl = hg * 16 + hh;
        float ar = 0.f, ai = 0.f;
#pragma unroll
        for (int k = 0; k < 32; ++k) {
            const float hrv = lhr[hl * 32 + k], hiv = lhi[hl * 32 + k];
            ar = fmaf(Pr[k], hrv, fmaf(Pi[k], hiv, ar));
            ai = fmaf(Pi[k], hrv, fmaf(-Pr[k], hiv, ai));
        }
        const int h = hq * 64 + hl;
        const size_t rb = ((size_t)(b * 256 + h) * 64 + o) * 64;
        recO[rb + m]      = f2b(ar);
        recO[rb + 32 + m] = f2b(ai);
    }
}

// K7: MFMA fused final. grid = B*H*4 (4096): (b,h,wq). 64 px/block, 4 waves.
__global__ __launch_bounds__(256) void k_final4(
    const float* __restrict__ x,
    const unsigned short* __restrict__ wb_bf,
    const unsigned short* __restrict__ recO,
    const float* __restrict__ mw, const float* __restrict__ mb,
    const float* __restrict__ scw, const float* __restrict__ scb,
    float* __restrict__ out)
{
    constexpr int LD = 72;
    __shared__ __align__(16) unsigned short sWb[64 * LD];
    __shared__ __align__(16) unsigned short sR [64 * LD];
    __shared__ __align__(16) unsigned short sX [64 * LD];
    __shared__ __align__(16) unsigned short sS [64 * LD];
    const int blk = blockIdx.x;
    const int b = blk >> 10, h = (blk >> 2) & 255, wq = blk & 3;
    const int w0 = wq * 64;
    const int t = threadIdx.x;
    const int lane = t & 63, wv = t >> 6;
    const size_t pixbase = (size_t)(b * 256 + h) * 256 + w0;

#pragma unroll
    for (int r = 0; r < 2; ++r) {
        const int idx = r * 256 + t;
        const int px = idx >> 3, f = idx & 7;
        *(uint4*)&sWb[px * LD + f * 8] = *(const uint4*)&wb_bf[(pixbase + px) * 64 + f * 8];
    }
    const size_t recbase = (size_t)(b * 256 + h) * 4096;
#pragma unroll
    for (int r = 0; r < 2; ++r) {
        const int idx = r * 256 + t;
        const int o = idx >> 3, f = idx & 7;
        *(uint4*)&sR[o * LD + f * 8] = *(const uint4*)&recO[recbase + (size_t)o * 64 + f * 8];
    }
#pragma unroll
    for (int r = 0; r < 4; ++r) {
        const int idx = r * 256 + t;
        const int c = idx >> 4, wg = idx & 15;
        const float4 v = *(const float4*)&x[((size_t)(b * 64 + c) * 256 + h) * 256 + w0 + wg * 4];
        sX[(wg * 4 + 0) * LD + c] = f2b(v.x);
        sX[(wg * 4 + 1) * LD + c] = f2b(v.y);
        sX[(wg * 4 + 2) * LD + c] = f2b(v.z);
        sX[(wg * 4 + 3) * LD + c] = f2b(v.w);
    }
    __syncthreads();

    const int arow = lane & 15;
    const int koff = (lane >> 4) * 8;
    const f32x4 zero = {0.f, 0.f, 0.f, 0.f};

    f32x4 accA[4] = {zero, zero, zero, zero};
#pragma unroll
    for (int kc = 0; kc < 2; ++kc) {
        const bf16x8 a = *(const bf16x8*)&sR[(16 * wv + arow) * LD + kc * 32 + koff];
#pragma unroll
        for (int nt = 0; nt < 4; ++nt) {
            const bf16x8 bb = *(const bf16x8*)&sWb[(nt * 16 + arow) * LD + kc * 32 + koff];
            accA[nt] = __builtin_amdgcn_mfma_f32_16x16x32_bf16(a, bb, accA[nt], 0, 0, 0);
        }
    }
    __syncthreads();

    const int crow = 16 * wv + (lane >> 4) * 4;
#pragma unroll
    for (int nt = 0; nt < 4; ++nt) {
        const int px = nt * 16 + arow;
#pragma unroll
        for (int j = 0; j < 4; ++j)
            sS[px * LD + crow + j] = f2b(accA[nt][j] * (1.0f / 65536.0f));
    }
#pragma unroll
    for (int r = 0; r < 4; ++r) {
        const int idx = r * 256 + t;
        const int o = idx >> 4, cq = idx & 15;
        const float4 v1 = *(const float4*)&mw[o * 64 + cq * 4];
        ushort4 u1;
        u1.x = f2b(v1.x); u1.y = f2b(v1.y); u1.z = f2b(v1.z); u1.w = f2b(v1.w);
        *(ushort4*)&sWb[o * LD + cq * 4] = u1;
        const float4 v2 = *(const float4*)&scw[o * 64 + cq * 4];
        ushort4 u2;
        u2.x = f2b(v2.x); u2.y = f2b(v2.y); u2.z = f2b(v2.z); u2.w = f2b(v2.w);
        *(ushort4*)&sR[o * LD + cq * 4] = u2;
    }
    __syncthreads();

    f32x4 accB[4] = {zero, zero, zero, zero};
    f32x4 accC[4] = {zero, zero, zero, zero};
#pragma unroll
    for (int kc = 0; kc < 2; ++kc) {
        const bf16x8 am = *(const bf16x8*)&sWb[(16 * wv + arow) * LD + kc * 32 + koff];
        const bf16x8 as = *(const bf16x8*)&sR [(16 * wv + arow) * LD + kc * 32 + koff];
#pragma unroll
        for (int nt = 0; nt < 4; ++nt) {
            const bf16x8 bs = *(const bf16x8*)&sS[(nt * 16 + arow) * LD + kc * 32 + koff];
            const bf16x8 bx = *(const bf16x8*)&sX[(nt * 16 + arow) * LD + kc * 32 + koff];
            accB[nt] = __builtin_amdgcn_mfma_f32_16x16x32_bf16(am, bs, accB[nt], 0, 0, 0);
            accC[nt] = __builtin_amdgcn_mfma_f32_16x16x32_bf16(as, bx, accC[nt], 0, 0, 0);
        }
    }

#pragma unroll
    for (int nt = 0; nt < 4; ++nt) {
        const int px = nt * 16 + arow;
#pragma unroll
        for (int j = 0; j < 4; ++j) {
            const int o = crow + j;
            const float y = gelu_f(accB[nt][j] + mb[o]);
            const float z = y + accC[nt][j] + scb[o];
            out[((size_t)(b * 64 + o) * 256 + h) * 256 + w0 + px] = gelu_f(z);
        }
    }
}

extern "C" void kernel_launch(void* const* d_in, const int* in_sizes, int n_in,
                              void* d_out, int out_size, void* d_ws, size_t ws_size,
                              hipStream_t stream) {
    const float* x    = (const float*)d_in[0];
    const float* wW0  = (const float*)d_in[1];
    const float* wb0  = (const float*)d_in[2];
    const float* wW1  = (const float*)d_in[3];
    const float* wb1  = (const float*)d_in[4];
    const float* wW2  = (const float*)d_in[5];
    const float* wb2  = (const float*)d_in[6];
    const float* hW0  = (const float*)d_in[7];
    const float* hb0  = (const float*)d_in[8];
    const float* hW1  = (const float*)d_in[9];
    const float* hb1  = (const float*)d_in[10];
    const float* hW2  = (const float*)d_in[11];
    const float* hb2  = (const float*)d_in[12];
    const float* Wf_re = (const float*)d_in[13];
    const float* Wf_im = (const float*)d_in[14];
    const float* mw   = (const float*)d_in[15];
    const float* mbv  = (const float*)d_in[16];
    const float* scw  = (const float*)d_in[17];
    const float* scb  = (const float*)d_in[18];

    char* base = (char*)d_ws;
    unsigned short* wb_bf = (unsigned short*)base;                         // 33,554,432 B
    float* tfwM    = (float*)(base + 33554432);                            // 16,777,216 B
    unsigned short* hb_bf = (unsigned short*)(base + 50331648);            //  4,194,304 B
    float* tfhw_re = (float*)(base + 54525952);                            //  1,048,576 B
    float* tfhw_im = (float*)(base + 55574528);
    float* proc_re = (float*)(base + 56623104);
    float* proc_im = (float*)(base + 57671680);
    unsigned short* recO = (unsigned short*)(base + 58720256);             //  8,388,608 B
    unsigned short* wT0 = (unsigned short*)(base + 67108864);              //     12,288 B
    unsigned short* wT1 = (unsigned short*)(base + 67121152);              //      8,192 B
    unsigned short* wT2 = (unsigned short*)(base + 67129344);
    unsigned short* hT0 = (unsigned short*)(base + 67137536);
    unsigned short* hT1 = (unsigned short*)(base + 67149824);
    unsigned short* hT2 = (unsigned short*)(base + 67158016);
    // total ~67.2 MB

    k_prep<<<1, 256, 0, stream>>>(wW0, wW1, wW2, hW0, hW1, hW2,
                                  wT0, wT1, wT2, hT0, hT1, hT2);
    k_wb_mlp2<<<4096, 256, 0, stream>>>(x, wT0, wb0, wT1, wb1, wT2, wb2, wb_bf);
    k_tfw<<<1024, 256, 0, stream>>>(x, wb_bf, tfwM);
    k_hb_mlp2<<<512, 256, 0, stream>>>(tfwM, hT0, hb0, hT1, hb1, hT2, hb2, hb_bf);
    k_tfhw2<<<256, 256, 0, stream>>>(tfwM, hb_bf, tfhw_re, tfhw_im);
    k_proc<<<256, 256, 0, stream>>>(tfhw_re, tfhw_im, Wf_re, Wf_im, proc_re, proc_im);
    k_rec2<<<512, 256, 0, stream>>>(proc_re, proc_im, hb_bf, recO);
    k_final4<<<4096, 256, 0, stream>>>(x, wb_bf, recO, mw, mbv, scw, scb, (float*)d_out);
}